// Round 6
// baseline (66.492 us; speedup 1.0000x reference)
//
#include <hip/hip_runtime.h>

#define B_      64
#define L_      8192
#define NB_     20
#define K_      769
#define GLEN    1537        // 2K-1 combined filter length
#define GSM     1552        // g row length (f32), = 97*16
#define NSTEP   97
#define NSTEPP  104         // padded steps (zeros beyond 97) for blind prefetch
#define TB      512         // t-tile per block
#define CPS_H   2072        // copy stride (halves): 16B-aligned, quad-skew 3 (coprime 8)
#define NW      2072        // staged halves per copy
#define XCP_N   (8 * CPS_H + 160)   // + pad: blind ring prefetch past last stripe
#define PADLEN  2307        // min(3K, L-1)
#define OFFSET  1539        // PADLEN - (K-1)
#define PBUF    (NB_ * GSM) // partial-g buffer stride (floats)

typedef _Float16 half8  __attribute__((ext_vector_type(8)));
typedef float    f32x16 __attribute__((ext_vector_type(16)));

// ---------------------------------------------------------------------------
// Kernel 1: partial autocorrelation. grid (NB, 8, 4): j-range split 4-way.
// ---------------------------------------------------------------------------
__global__ __launch_bounds__(256) void bp_combine(
    const float* __restrict__ kern, float* __restrict__ gpart)
{
    __shared__ __align__(16) float ks[K_];
    const int o   = blockIdx.x;
    const int jc  = blockIdx.z;
    const int tid = threadIdx.x;
    for (int i = tid; i < K_; i += 256) ks[i] = kern[o * K_ + i];
    __syncthreads();

    const int m = blockIdx.y * 194 + tid;
    if (tid < 194 && m < GSM) {
        float acc = 0.f;
        int jlo = (m > K_ - 1) ? (m - (K_ - 1)) : 0;
        int jhi = (m < K_ - 1) ? m : (K_ - 1);
        if (jlo < jc * 193) jlo = jc * 193;
        if (jhi > jc * 193 + 192) jhi = jc * 193 + 192;
        for (int j = jlo; j <= jhi; ++j)
            acc = fmaf(ks[K_ - 1 - j], ks[m - j], acc);
        gpart[jc * PBUF + o * GSM + m] = acc;
    }
}

// ---------------------------------------------------------------------------
// Kernel 2: sum partials, scale x1024, pack into MFMA A-fragment layout (f16).
// Fragment t = step*64 + l: elem e = g1024[o = l&31, 16*step + 8*(l>>5) + e]
// ---------------------------------------------------------------------------
__global__ __launch_bounds__(256) void bp_pack(
    const float* __restrict__ gpart, _Float16* __restrict__ gbuf)
{
    const int t = blockIdx.x * 256 + threadIdx.x;
    if (t >= NSTEPP * 64) return;
    const int step = t >> 6;
    const int l    = t & 63;
    const int o    = l & 31;
    const int h5   = l >> 5;
    half8 f;
    #pragma unroll
    for (int e = 0; e < 8; ++e) {
        const int tap = 16 * step + 8 * h5 + e;
        float v = 0.f;
        if (o < NB_ && tap < GLEN) {
            const int idx = o * GSM + tap;
            v = (gpart[idx] + gpart[PBUF + idx] +
                 gpart[2 * PBUF + idx] + gpart[3 * PBUF + idx]) * 1024.0f;
        }
        f[e] = (_Float16)v;
    }
    *((half8*)gbuf + t) = f;
}

// ---------------------------------------------------------------------------
// Kernel 3: C[o, t] = sum_k g[o,k] * Toeplitz(xp)[k, t] via mfma 32x32x16 f16.
// Barrier-free K-loop: x fragments from 8 parity-shifted LDS copies through
// rotating rings E[4]/O[4] (1 ds_read_b128/step); g fragments from global
// (L1/L2-resident) through a 4-deep static register ring (prefetch dist 4).
// 4 blocks/CU exactly (1024 blocks resident), no in-loop syncs.
// ---------------------------------------------------------------------------
__global__ __launch_bounds__(256, 4) void bp_mfma(
    const float* __restrict__ x, const _Float16* __restrict__ gbuf,
    float* __restrict__ out)
{
    __shared__ __align__(16) _Float16 xcp[XCP_N];   // 33.5 KB

    const int blk  = blockIdx.x;
    const int tile = blk & 15;              // L/TB = 16
    const int b    = blk >> 4;
    const int tid  = threadIdx.x;
    const int l    = tid & 63;
    const int w    = tid >> 6;

    const int T0 = tile * TB;
    const float* __restrict__ xrow = x + b * L_;

    // stage reflected window as f16, 8 parity-shifted copies
    for (int i = tid; i < NW; i += 256) {
        const int p = T0 + OFFSET + i;
        float v;
        if (p < PADLEN)            v = -xrow[PADLEN - p];
        else if (p < PADLEN + L_)  v =  xrow[p - PADLEN];
        else                       v = -xrow[(L_ - 2) + (PADLEN + L_) - p];
        const _Float16 h = (_Float16)v;
        #pragma unroll
        for (int cc = 0; cc < 8; ++cc) {
            const int j = i - cc;
            if (j >= 0) xcp[cc * CPS_H + j] = h;
        }
    }
    __syncthreads();          // the only barrier

    const int c  = l & 7;
    const int u  = l & 31;
    const int h5 = l >> 5;

    f32x16 acc[4];
    #pragma unroll
    for (int q = 0; q < 4; ++q)
        #pragma unroll
        for (int r = 0; r < 16; ++r) acc[q][r] = 0.f;

    // fragment base: 16B-aligned via parity copy c = l&7
    const char* lb0 = (const char*)xcp + c * (CPS_H * 2)
                    + 2 * (128 * w + u + 8 * h5 - c);

    half8 E[4], O[4];
    #pragma unroll
    for (int j = 0; j < 4; ++j) {
        E[j] = *(const half8*)(lb0 + 64 * j);
        O[j] = *(const half8*)(lb0 + 32 + 64 * j);
    }

    // g register ring: gq[s&3] holds step s; refill with step s+4 after use
    const half8* __restrict__ gp = (const half8*)gbuf + l;
    half8 gq[4];
    #pragma unroll
    for (int j = 0; j < 4; ++j) gq[j] = gp[64 * j];

    const char* lbm = lb0 + 256;            // refill base for octave m
    const half8* gpm = gp + 64 * 4;         // g prefetch base for octave m

    for (int m = 0; m < 12; ++m) {
        #pragma unroll
        for (int u8 = 0; u8 < 8; ++u8) {
            const int hh = (u8 >> 1) & 3;   // static: (s>>1)&3, 4m&3==0
            const int gs = u8 & 3;          // static: s&3
            if ((u8 & 1) == 0) {
                acc[0] = __builtin_amdgcn_mfma_f32_32x32x16_f16(gq[gs], E[(hh + 0) & 3], acc[0], 0, 0, 0);
                acc[1] = __builtin_amdgcn_mfma_f32_32x32x16_f16(gq[gs], E[(hh + 1) & 3], acc[1], 0, 0, 0);
                acc[2] = __builtin_amdgcn_mfma_f32_32x32x16_f16(gq[gs], E[(hh + 2) & 3], acc[2], 0, 0, 0);
                acc[3] = __builtin_amdgcn_mfma_f32_32x32x16_f16(gq[gs], E[(hh + 3) & 3], acc[3], 0, 0, 0);
                E[hh] = *(const half8*)(lbm + 32 * u8);     // fragment for step s+8
            } else {
                acc[0] = __builtin_amdgcn_mfma_f32_32x32x16_f16(gq[gs], O[(hh + 0) & 3], acc[0], 0, 0, 0);
                acc[1] = __builtin_amdgcn_mfma_f32_32x32x16_f16(gq[gs], O[(hh + 1) & 3], acc[1], 0, 0, 0);
                acc[2] = __builtin_amdgcn_mfma_f32_32x32x16_f16(gq[gs], O[(hh + 2) & 3], acc[2], 0, 0, 0);
                acc[3] = __builtin_amdgcn_mfma_f32_32x32x16_f16(gq[gs], O[(hh + 3) & 3], acc[3], 0, 0, 0);
                O[hh] = *(const half8*)(lbm + 32 * u8);
            }
            gq[gs] = gpm[64 * u8];          // g step s+4 (zeros beyond 96: safe)
        }
        lbm += 256;
        gpm += 64 * 8;
    }

    // tail: step 96 (even, h=0): E[j] holds fragment (q=j, s=96)
    acc[0] = __builtin_amdgcn_mfma_f32_32x32x16_f16(gq[0], E[0], acc[0], 0, 0, 0);
    acc[1] = __builtin_amdgcn_mfma_f32_32x32x16_f16(gq[0], E[1], acc[1], 0, 0, 0);
    acc[2] = __builtin_amdgcn_mfma_f32_32x32x16_f16(gq[0], E[2], acc[2], 0, 0, 0);
    acc[3] = __builtin_amdgcn_mfma_f32_32x32x16_f16(gq[0], E[3], acc[3], 0, 0, 0);

    // D layout: col = l&31 (t-local), row = (r&3)+8*(r>>2)+4*(l>>5) (o)
    const float sc = 1.0f / 1024.0f;
    #pragma unroll
    for (int q = 0; q < 4; ++q) {
        const int tb = T0 + 32 * (4 * w + q) + u;
        #pragma unroll
        for (int r = 0; r < 16; ++r) {
            const int o = (r & 3) + 8 * (r >> 2) + 4 * h5;
            if (o < NB_)
                out[((b * NB_ + o) << 13) + tb] = acc[q][r] * sc;
        }
    }
}

extern "C" void kernel_launch(void* const* d_in, const int* in_sizes, int n_in,
                              void* d_out, int out_size, void* d_ws, size_t ws_size,
                              hipStream_t stream)
{
    const float* x    = (const float*)d_in[0];   // (B,1,L) f32
    const float* kern = (const float*)d_in[1];   // (NB,K) f32
    float*       out  = (float*)d_out;           // (B,1,NB,L) f32

    float*    gpart = (float*)d_ws;                           // 496640 B
    _Float16* gbuf  = (_Float16*)((char*)d_ws + 496640);      // 104 KB

    bp_combine<<<dim3(NB_, 8, 4), 256, 0, stream>>>(kern, gpart);
    bp_pack<<<26, 256, 0, stream>>>(gpart, gbuf);
    bp_mfma<<<B_ * (L_ / TB), 256, 0, stream>>>(x, gbuf, out);
}

// Round 7
// 58.616 us; speedup vs baseline: 1.1344x; 1.1344x over previous
//
#include <hip/hip_runtime.h>

#define B_      64
#define L_      8192
#define NB_     20
#define K_      769
#define GLEN    1537        // 2K-1 combined filter length
#define GSM     1552        // g row length (f32), = 97*16
#define NSTEP   97
#define NSTEPP  104         // padded steps (zeros beyond 97) for blind prefetch
#define TB      512         // t-tile per block
#define CPS_H   2072        // copy stride (halves): 16B-aligned, quad-skew 3 (coprime 8)
#define NW      2072        // staged halves per copy
#define XCP_N   (8 * CPS_H + 160)   // + pad: blind ring prefetch past last stripe
#define PADLEN  2307        // min(3K, L-1)
#define OFFSET  1539        // PADLEN - (K-1)
#define PBUF    (NB_ * GSM) // partial-g buffer stride (floats)

typedef _Float16 half8  __attribute__((ext_vector_type(8)));
typedef float    f32x16 __attribute__((ext_vector_type(16)));

// ---------------------------------------------------------------------------
// Kernel 1: partial autocorrelation. grid (NB, 8, 4): j-range split 4-way.
// ---------------------------------------------------------------------------
__global__ __launch_bounds__(256) void bp_combine(
    const float* __restrict__ kern, float* __restrict__ gpart)
{
    __shared__ __align__(16) float ks[K_];
    const int o   = blockIdx.x;
    const int jc  = blockIdx.z;
    const int tid = threadIdx.x;
    for (int i = tid; i < K_; i += 256) ks[i] = kern[o * K_ + i];
    __syncthreads();

    const int m = blockIdx.y * 194 + tid;
    if (tid < 194 && m < GSM) {
        float acc = 0.f;
        int jlo = (m > K_ - 1) ? (m - (K_ - 1)) : 0;
        int jhi = (m < K_ - 1) ? m : (K_ - 1);
        if (jlo < jc * 193) jlo = jc * 193;
        if (jhi > jc * 193 + 192) jhi = jc * 193 + 192;
        for (int j = jlo; j <= jhi; ++j)
            acc = fmaf(ks[K_ - 1 - j], ks[m - j], acc);
        gpart[jc * PBUF + o * GSM + m] = acc;
    }
}

// ---------------------------------------------------------------------------
// Kernel 2: sum partials, scale x1024, pack into MFMA A-fragment layout (f16).
// Fragment t = step*64 + l: elem e = g1024[o = l&31, 16*step + 8*(l>>5) + e]
// ---------------------------------------------------------------------------
__global__ __launch_bounds__(256) void bp_pack(
    const float* __restrict__ gpart, _Float16* __restrict__ gbuf)
{
    const int t = blockIdx.x * 256 + threadIdx.x;
    if (t >= NSTEPP * 64) return;
    const int step = t >> 6;
    const int l    = t & 63;
    const int o    = l & 31;
    const int h5   = l >> 5;
    half8 f;
    #pragma unroll
    for (int e = 0; e < 8; ++e) {
        const int tap = 16 * step + 8 * h5 + e;
        float v = 0.f;
        if (o < NB_ && tap < GLEN) {
            const int idx = o * GSM + tap;
            v = (gpart[idx] + gpart[PBUF + idx] +
                 gpart[2 * PBUF + idx] + gpart[3 * PBUF + idx]) * 1024.0f;
        }
        f[e] = (_Float16)v;
    }
    *((half8*)gbuf + t) = f;
}

// ---------------------------------------------------------------------------
// Kernel 3: C[o, t] = sum_k g[o,k] * Toeplitz(xp)[k, t] via mfma 32x32x16 f16.
// Barrier-free K-loop; x fragments via 8 parity-shifted LDS copies + rotating
// rings E[4]/O[4]; g via 4-deep global register ring (L2-resident now that
// output stores are non-temporal and stop thrashing L2). setprio around MFMA.
// ---------------------------------------------------------------------------
__global__ __launch_bounds__(256, 4) void bp_mfma(
    const float* __restrict__ x, const _Float16* __restrict__ gbuf,
    float* __restrict__ out)
{
    __shared__ __align__(16) _Float16 xcp[XCP_N];   // 33.5 KB

    const int blk  = blockIdx.x;
    const int tile = blk & 15;              // L/TB = 16
    const int b    = blk >> 4;
    const int tid  = threadIdx.x;
    const int l    = tid & 63;
    const int w    = tid >> 6;

    const int T0 = tile * TB;
    const float* __restrict__ xrow = x + b * L_;

    // ---- two-phase staging: 9 independent loads first, then LDS writes ----
    float xv[9];
    #pragma unroll
    for (int r = 0; r < 9; ++r) {
        const int i = tid + 256 * r;
        if (i < NW) {
            const int p = T0 + OFFSET + i;
            float v;
            if (p < PADLEN)            v = -xrow[PADLEN - p];
            else if (p < PADLEN + L_)  v =  xrow[p - PADLEN];
            else                       v = -xrow[(L_ - 2) + (PADLEN + L_) - p];
            xv[r] = v;
        }
    }
    #pragma unroll
    for (int r = 0; r < 9; ++r) {
        const int i = tid + 256 * r;
        if (i < NW) {
            const _Float16 h = (_Float16)xv[r];
            #pragma unroll
            for (int cc = 0; cc < 8; ++cc) {
                const int j = i - cc;
                if (j >= 0) xcp[cc * CPS_H + j] = h;
            }
        }
    }
    __syncthreads();          // the only barrier

    const int c  = l & 7;
    const int u  = l & 31;
    const int h5 = l >> 5;

    f32x16 acc[4];
    #pragma unroll
    for (int q = 0; q < 4; ++q)
        #pragma unroll
        for (int r = 0; r < 16; ++r) acc[q][r] = 0.f;

    // fragment base: 16B-aligned via parity copy c = l&7
    const char* lb0 = (const char*)xcp + c * (CPS_H * 2)
                    + 2 * (128 * w + u + 8 * h5 - c);

    half8 E[4], O[4];
    #pragma unroll
    for (int j = 0; j < 4; ++j) {
        E[j] = *(const half8*)(lb0 + 64 * j);
        O[j] = *(const half8*)(lb0 + 32 + 64 * j);
    }

    // g register ring: gq[s&3] holds step s; refill with step s+4 after use
    const half8* __restrict__ gp = (const half8*)gbuf + l;
    half8 gq[4];
    #pragma unroll
    for (int j = 0; j < 4; ++j) gq[j] = gp[64 * j];

    const char* lbm = lb0 + 256;            // refill base for octave m
    const half8* gpm = gp + 64 * 4;         // g prefetch base for octave m

    for (int m = 0; m < 12; ++m) {
        #pragma unroll
        for (int u8 = 0; u8 < 8; ++u8) {
            const int hh = (u8 >> 1) & 3;   // static: (s>>1)&3, 4m&3==0
            const int gs = u8 & 3;          // static: s&3
            __builtin_amdgcn_s_setprio(1);
            if ((u8 & 1) == 0) {
                acc[0] = __builtin_amdgcn_mfma_f32_32x32x16_f16(gq[gs], E[(hh + 0) & 3], acc[0], 0, 0, 0);
                acc[1] = __builtin_amdgcn_mfma_f32_32x32x16_f16(gq[gs], E[(hh + 1) & 3], acc[1], 0, 0, 0);
                acc[2] = __builtin_amdgcn_mfma_f32_32x32x16_f16(gq[gs], E[(hh + 2) & 3], acc[2], 0, 0, 0);
                acc[3] = __builtin_amdgcn_mfma_f32_32x32x16_f16(gq[gs], E[(hh + 3) & 3], acc[3], 0, 0, 0);
                __builtin_amdgcn_s_setprio(0);
                E[hh] = *(const half8*)(lbm + 32 * u8);     // fragment for step s+8
            } else {
                acc[0] = __builtin_amdgcn_mfma_f32_32x32x16_f16(gq[gs], O[(hh + 0) & 3], acc[0], 0, 0, 0);
                acc[1] = __builtin_amdgcn_mfma_f32_32x32x16_f16(gq[gs], O[(hh + 1) & 3], acc[1], 0, 0, 0);
                acc[2] = __builtin_amdgcn_mfma_f32_32x32x16_f16(gq[gs], O[(hh + 2) & 3], acc[2], 0, 0, 0);
                acc[3] = __builtin_amdgcn_mfma_f32_32x32x16_f16(gq[gs], O[(hh + 3) & 3], acc[3], 0, 0, 0);
                __builtin_amdgcn_s_setprio(0);
                O[hh] = *(const half8*)(lbm + 32 * u8);
            }
            gq[gs] = gpm[64 * u8];          // g step s+4 (zeros beyond 96: safe)
        }
        lbm += 256;
        gpm += 64 * 8;
    }

    // tail: step 96 (even, h=0): E[j] holds fragment (q=j, s=96)
    __builtin_amdgcn_s_setprio(1);
    acc[0] = __builtin_amdgcn_mfma_f32_32x32x16_f16(gq[0], E[0], acc[0], 0, 0, 0);
    acc[1] = __builtin_amdgcn_mfma_f32_32x32x16_f16(gq[0], E[1], acc[1], 0, 0, 0);
    acc[2] = __builtin_amdgcn_mfma_f32_32x32x16_f16(gq[0], E[2], acc[2], 0, 0, 0);
    acc[3] = __builtin_amdgcn_mfma_f32_32x32x16_f16(gq[0], E[3], acc[3], 0, 0, 0);
    __builtin_amdgcn_s_setprio(0);

    // D layout: col = l&31 (t-local), row = (r&3)+8*(r>>2)+4*(l>>5) (o)
    // Non-temporal stores: keep the 42 MB output stream from evicting gbuf
    // (100 KB, re-read every step by every wave) out of L2.
    const float sc = 1.0f / 1024.0f;
    #pragma unroll
    for (int q = 0; q < 4; ++q) {
        const int tb = T0 + 32 * (4 * w + q) + u;
        #pragma unroll
        for (int r = 0; r < 16; ++r) {
            const int o = (r & 3) + 8 * (r >> 2) + 4 * h5;
            if (o < NB_)
                __builtin_nontemporal_store(acc[q][r] * sc,
                                            &out[((b * NB_ + o) << 13) + tb]);
        }
    }
}

extern "C" void kernel_launch(void* const* d_in, const int* in_sizes, int n_in,
                              void* d_out, int out_size, void* d_ws, size_t ws_size,
                              hipStream_t stream)
{
    const float* x    = (const float*)d_in[0];   // (B,1,L) f32
    const float* kern = (const float*)d_in[1];   // (NB,K) f32
    float*       out  = (float*)d_out;           // (B,1,NB,L) f32

    float*    gpart = (float*)d_ws;                           // 496640 B
    _Float16* gbuf  = (_Float16*)((char*)d_ws + 496640);      // 104 KB

    bp_combine<<<dim3(NB_, 8, 4), 256, 0, stream>>>(kern, gpart);
    bp_pack<<<26, 256, 0, stream>>>(gpart, gbuf);
    bp_mfma<<<B_ * (L_ / TB), 256, 0, stream>>>(x, gbuf, out);
}